// Round 4
// baseline (203.807 us; speedup 1.0000x reference)
//
#include <hip/hip_runtime.h>
#include <hip/hip_bf16.h>
#include <math.h>

// Problem constants
#define BB   256   // batch
#define TT   256   // sequence
#define CIN  384   // n_embed
#define HS   64    // head size

// softmax scale folded into q at projection time: 384^-0.5 * log2(e)
#define QSCL ((float)(0.051031036307982884 * 1.4426950408889634))

typedef __attribute__((ext_vector_type(8))) short short8;   // 8 bf16 = 4 VGPR
typedef __attribute__((ext_vector_type(4))) float floatx4;  // MFMA C/D

__device__ inline short bf16bits(float f) {
    union { __hip_bfloat16 h; short s; } u;
    u.h = __float2bfloat16(f);
    return u.s;
}

__device__ inline short8 cvt8(const float4& f0, const float4& f1) {
    union { __hip_bfloat162 h[4]; short8 s8; } u;
    u.h[0] = __float22bfloat162_rn(make_float2(f0.x, f0.y));
    u.h[1] = __float22bfloat162_rn(make_float2(f0.z, f0.w));
    u.h[2] = __float22bfloat162_rn(make_float2(f1.x, f1.y));
    u.h[3] = __float22bfloat162_rn(make_float2(f1.z, f1.w));
    return u.s8;
}

// ---------------------------------------------------------------------------
// Kernel 0 (unchanged): pack Wq|Wk|Wv into WtP, frag-contiguous bf16:
// X = ((h*6+s)*2+ks)*6+nt; element (l15,quad,j) at X*512 + l15*32 + quad*8 + j.
// One B-frag wave load = ONE aligned 1 KB segment.
// ---------------------------------------------------------------------------
__global__ __launch_bounds__(256) void prep_wtp(
    const float* __restrict__ Wq, const float* __restrict__ Wk,
    const float* __restrict__ Wv, short* __restrict__ WtP)
{
    const int idx  = blockIdx.x * 256 + threadIdx.x;   // 0 .. 73727
    const int j    = idx & 7;
    const int quad = (idx >> 3) & 3;
    const int l15  = (idx >> 5) & 15;
    int X          = idx >> 9;          // 0..143
    const int nt   = X % 6;  X /= 6;
    const int ks   = X & 1;  X >>= 1;
    const int s    = X % 6;  X /= 6;
    const int wn   = X;                 // 0..1

    const int n  = wn * 96 + nt * 16 + l15;        // output column 0..191
    const int kk = s * 64 + ks * 32 + quad * 8 + j; // k index 0..383
    const float* W = (n < 64) ? Wq : (n < 128) ? Wk : Wv;
    WtP[idx] = bf16bits(W[kk * 64 + (n & 63)]);
}

// ---------------------------------------------------------------------------
// FUSED kernel: one block per batch element, 1024 threads = 16 waves.
//
// Phase 1: barrier-free, LDS-free GEMM; wave w owns rows [w*16,w*16+16) x
//   N=192 (acc[12] = 48 VGPR). ROUND-3 FAILURE: compiler allocated only 56
//   VGPR (48 = acc) and serialized all 144 B-frag loads into one-at-a-time
//   vmcnt(0) round trips (~220 cyc L2 latency each) -> every pipe <8% busy.
//   FIX: explicit 12-wide load batches bA[12]/bB[12] terminated by
//   __builtin_amdgcn_sched_barrier(0) -- the scheduler cannot sink the
//   loads below the barrier, so each batch issues back-to-back and pays
//   ONE latency instead of twelve. Peak regs: 48 acc + 48 batch + 8 af +
//   16 nxt + addr ~= 124 <= 128 cap (no spill by budget).
// Epilogue: q/k/vT scattered to frag-contiguous LDS (each phase-2 frag =
//   one linear 1 KB segment => conflict-free ds_read_b128).
// Single __syncthreads. Phase 2: wave w owns query group g=w (the same 16
//   rows it computed): causal chunks, unnormalized exp2 softmax,
//   wave-private Ps, PV from vP, fp32 out.
//
// LDS (shorts): qP[0): [(g*2+h)*16+row][32]            = 16384
//               kP[16384): [((c*2+t)*2+h)*16+key15][32] = 16384
//               vP[32768): [(c*4+nb)*16+vcol15][32]     = 16384
//               Ps[49152): [w][16][40]                  = 10240
//               total 59392 shorts = 118784 B -> 1 block/CU, 16 waves.
// ---------------------------------------------------------------------------
__global__ __launch_bounds__(1024, 4) void fused_head(
    const float* __restrict__ x, const short* __restrict__ WtP,
    float* __restrict__ out)
{
    __shared__ short smem[59392];   // 118784 B

    const int tid  = threadIdx.x;
    const int b    = blockIdx.x;
    const int lane = tid & 63;
    const int w    = tid >> 6;        // 0..15
    const int l15  = lane & 15;
    const int quad = lane >> 4;
    const int kq   = quad * 8;
    const int crow = quad * 4;

    const float* xb = x + (size_t)b * 256 * 384;
    const int laneoff = l15 * 32 + kq;       // WtP per-lane offset

    // ---- phase 1: barrier-free, LDS-free GEMM with FORCED load batching -
    floatx4 acc[12] = {};

    const float* xr = xb + (size_t)(w * 16 + l15) * 384 + kq;

    float4 c00 = *(const float4*)(xr + 0);
    float4 c01 = *(const float4*)(xr + 4);
    float4 c10 = *(const float4*)(xr + 32);
    float4 c11 = *(const float4*)(xr + 36);

#pragma unroll
    for (int s = 0; s < 6; ++s) {
        // --- batch 1: x prefetch (HBM) + all 12 ks=0 B-frags (L2) --------
        float4 n00, n01, n10, n11;
        if (s < 5) {
            n00 = *(const float4*)(xr + (s + 1) * 64 + 0);
            n01 = *(const float4*)(xr + (s + 1) * 64 + 4);
            n10 = *(const float4*)(xr + (s + 1) * 64 + 32);
            n11 = *(const float4*)(xr + (s + 1) * 64 + 36);
        }
        short8 bA[12];
#pragma unroll
        for (int j = 0; j < 12; ++j) {
            const int h = j / 6, nt = j % 6;
            bA[j] = *(const short8*)
                &WtP[((((h * 6 + s) * 2 + 0) * 6 + nt) << 9) + laneoff];
        }
        __builtin_amdgcn_sched_barrier(0);   // loads above may not sink

        const short8 af0 = cvt8(c00, c01);
        const short8 af1 = cvt8(c10, c11);
#pragma unroll
        for (int j = 0; j < 12; ++j)
            acc[j] = __builtin_amdgcn_mfma_f32_16x16x32_bf16(
                af0, bA[j], acc[j], 0, 0, 0);

        // --- batch 2: all 12 ks=1 B-frags --------------------------------
        short8 bB[12];
#pragma unroll
        for (int j = 0; j < 12; ++j) {
            const int h = j / 6, nt = j % 6;
            bB[j] = *(const short8*)
                &WtP[((((h * 6 + s) * 2 + 1) * 6 + nt) << 9) + laneoff];
        }
        __builtin_amdgcn_sched_barrier(0);

#pragma unroll
        for (int j = 0; j < 12; ++j)
            acc[j] = __builtin_amdgcn_mfma_f32_16x16x32_bf16(
                af1, bB[j], acc[j], 0, 0, 0);

        if (s < 5) { c00 = n00; c01 = n01; c10 = n10; c11 = n11; }
    }

    // ---- epilogue: scatter acc into frag-contiguous LDS -----------------
    short* qP = smem;            // [(g*2+h)*16 + qrow15][32]
    short* kP = smem + 16384;    // [((c*2+t)*2+h)*16 + key15][32]
    short* vP = smem + 32768;    // [(c*4+nb)*16 + vcol15][32]
    short* Ps = smem + 49152;    // [w][16][40]

#pragma unroll
    for (int j = 0; j < 12; ++j) {
#pragma unroll
        for (int r = 0; r < 4; ++r) {
            const int n  = j * 16 + l15;     // output column 0..191
            const int mr = crow + r;         // row within this wave's 16
            const float av = acc[j][r];
            if (j < 4) {
                const int h = j >> 1;
                qP[((w * 2 + h) * 16 + mr) * 32 + ((n & 31) >> 3) * 8 + (n & 7)]
                    = bf16bits(av * QSCL);
            } else if (j < 8) {
                const int h = (j - 4) >> 1;
                kP[((w * 2 + h) * 16 + mr) * 32 + (((n - 64) & 31) >> 3) * 8 + (n & 7)]
                    = bf16bits(av);
            } else {
                const int nb = j - 8;
                const int kk = (w & 1) * 16 + mr;      // key within 32-chunk
                vP[(((w >> 1) * 4 + nb) * 16 + l15) * 32 + kk] = bf16bits(av);
            }
        }
    }
    __syncthreads();

    // ---- phase 2: wave w owns query group g = w (16 rows) ---------------
    {
        const int g  = w;
        const int r0 = g * 16;

        const short8 aq0 = *(const short8*)&qP[((g * 2 + 0) * 16 + l15) * 32 + kq];
        const short8 aq1 = *(const short8*)&qP[((g * 2 + 1) * 16 + l15) * 32 + kq];

        float lsum[4] = {0.f, 0.f, 0.f, 0.f};
        floatx4 O[4] = {};

        const int nch = (r0 + 47) >> 5;   // causal chunk bound
        for (int c = 0; c < nch; ++c) {
            const int cb = c * 32;

            floatx4 st[2];
#pragma unroll
            for (int t = 0; t < 2; ++t) {
                const short8 b0 = *(const short8*)
                    &kP[(((c * 2 + t) * 2 + 0) * 16 + l15) * 32 + kq];
                const short8 b1 = *(const short8*)
                    &kP[(((c * 2 + t) * 2 + 1) * 16 + l15) * 32 + kq];
                floatx4 z = {};
                z = __builtin_amdgcn_mfma_f32_16x16x32_bf16(aq0, b0, z, 0, 0, 0);
                z = __builtin_amdgcn_mfma_f32_16x16x32_bf16(aq1, b1, z, 0, 0, 0);
                st[t] = z;
            }

#pragma unroll
            for (int t = 0; t < 2; ++t)
#pragma unroll
                for (int r = 0; r < 4; ++r) {
                    const int key  = cb + t * 16 + l15;
                    const int qrow = r0 + crow + r;
                    float p = __builtin_amdgcn_exp2f(st[t][r]);
                    p = (key <= qrow) ? p : 0.f;
                    lsum[r] += p;
                    Ps[w * 640 + (crow + r) * 40 + t * 16 + l15] = bf16bits(p);
                }

            // wave-private LDS write->read ordering
            asm volatile("s_waitcnt lgkmcnt(0)" ::: "memory");

            const short8 pa = *(const short8*)&Ps[w * 640 + l15 * 40 + kq];
#pragma unroll
            for (int n = 0; n < 4; ++n) {
                const short8 bv = *(const short8*)
                    &vP[((c * 4 + n) * 16 + l15) * 32 + kq];
                O[n] = __builtin_amdgcn_mfma_f32_16x16x32_bf16(pa, bv, O[n], 0, 0, 0);
            }
        }

#pragma unroll
        for (int off = 1; off < 16; off <<= 1)
#pragma unroll
            for (int r = 0; r < 4; ++r)
                lsum[r] += __shfl_xor(lsum[r], off, 16);

        float inv[4];
#pragma unroll
        for (int r = 0; r < 4; ++r) inv[r] = 1.f / lsum[r];
#pragma unroll
        for (int n = 0; n < 4; ++n)
#pragma unroll
            for (int r = 0; r < 4; ++r)
                out[(size_t)(b * 256 + r0 + crow + r) * 64 + n * 16 + l15]
                    = O[n][r] * inv[r];
    }
}

// ---------------------------------------------------------------------------
// Launch
// ---------------------------------------------------------------------------
extern "C" void kernel_launch(void* const* d_in, const int* in_sizes, int n_in,
                              void* d_out, int out_size, void* d_ws, size_t ws_size,
                              hipStream_t stream)
{
    const float* x  = (const float*)d_in[0];
    const float* Wq = (const float*)d_in[1];
    const float* Wk = (const float*)d_in[2];
    const float* Wv = (const float*)d_in[3];
    float* out = (float*)d_out;

    short* WtP = (short*)d_ws;   // 73728 bf16 = 147456 B

    prep_wtp<<<(192 * 384) / 256, 256, 0, stream>>>(Wq, Wk, Wv, WtP);
    fused_head<<<BB, 1024, 0, stream>>>(x, WtP, out);
}

// Round 6
// 198.167 us; speedup vs baseline: 1.0285x; 1.0285x over previous
//
#include <hip/hip_runtime.h>
#include <hip/hip_bf16.h>
#include <math.h>

// Problem constants
#define BB   256   // batch
#define TT   256   // sequence
#define CIN  384   // n_embed
#define HS   64    // head size

// softmax scale folded into q at projection time: 384^-0.5 * log2(e)
#define QSCL ((float)(0.051031036307982884 * 1.4426950408889634))

typedef __attribute__((ext_vector_type(8))) short short8;   // 8 bf16 = 4 VGPR
typedef __attribute__((ext_vector_type(4))) float floatx4;  // MFMA C/D
typedef __attribute__((ext_vector_type(4))) float fx4;      // plain clang vec4

__device__ inline short bf16bits(float f) {
    union { __hip_bfloat16 h; short s; } u;
    u.h = __float2bfloat16(f);
    return u.s;
}

__device__ inline short8 cvt8(const fx4& f0, const fx4& f1) {
    union { __hip_bfloat162 h[4]; short8 s8; } u;
    u.h[0] = __float22bfloat162_rn(make_float2(f0.x, f0.y));
    u.h[1] = __float22bfloat162_rn(make_float2(f0.z, f0.w));
    u.h[2] = __float22bfloat162_rn(make_float2(f1.x, f1.y));
    u.h[3] = __float22bfloat162_rn(make_float2(f1.z, f1.w));
    return u.s8;
}

// nontemporal fp32x4 load (clang ext_vector type -- HIP float4 is rejected)
__device__ inline fx4 ntload4(const float* p) {
    return __builtin_nontemporal_load((const fx4*)p);
}

// ---------------------------------------------------------------------------
// Kernel 0 (unchanged): pack Wq|Wk|Wv into WtP, frag-contiguous bf16:
// X = ((h*6+s)*2+ks)*6+nt; element (l15,quad,j) at X*512 + l15*32 + quad*8 + j.
// One B-frag wave load = ONE aligned 1 KB segment.
// ---------------------------------------------------------------------------
__global__ __launch_bounds__(256) void prep_wtp(
    const float* __restrict__ Wq, const float* __restrict__ Wk,
    const float* __restrict__ Wv, short* __restrict__ WtP)
{
    const int idx  = blockIdx.x * 256 + threadIdx.x;   // 0 .. 73727
    const int j    = idx & 7;
    const int quad = (idx >> 3) & 3;
    const int l15  = (idx >> 5) & 15;
    int X          = idx >> 9;          // 0..143
    const int nt   = X % 6;  X /= 6;
    const int ks   = X & 1;  X >>= 1;
    const int s    = X % 6;  X /= 6;
    const int wn   = X;                 // 0..1

    const int n  = wn * 96 + nt * 16 + l15;        // output column 0..191
    const int kk = s * 64 + ks * 32 + quad * 8 + j; // k index 0..383
    const float* W = (n < 64) ? Wq : (n < 128) ? Wk : Wv;
    WtP[idx] = bf16bits(W[kk * 64 + (n & 63)]);
}

// ---------------------------------------------------------------------------
// Kernel A: QKV projection GEMM, M=65536 x N=192 x K=384, batch-oblivious.
// 512 blocks x 512 threads (8 waves); wave handles 16 rows x 192 cols:
// acc[12] = 48 VGPR. ZERO LDS, ZERO barriers -> 2 blocks/CU co-resident,
// 16 waves/CU: L2 latency on B-frag batches is hidden by TLP (rounds 1-4
// proved in-block ILP cannot survive the 128-VGPR allocator cap; this
// design needs only ~104 regs peak: 48 acc + 24 B-batch + 16 A-cur + 8 af).
// x loads are nontemporal (streamed once; keeps L1 for the WtP slab that
// all 16 resident waves share). Outputs are written DIRECTLY in the
// frag-contiguous layouts kernel B consumes (one 1 KB segment per frag):
//   qF[((b*16+g)*2+h)*512 + row15*32 + kcol]  (pre-scaled by QSCL)
//   kF[((b*16+kb)*2+h)*512 + key15*32 + kcol]
//   vF[((b*4+nb)*8+c)*512 + vcol15*32 + keyInChunk]
// ---------------------------------------------------------------------------
__global__ __launch_bounds__(512, 2) void qkv_gemm(
    const float* __restrict__ x, const short* __restrict__ WtP,
    short* __restrict__ qF, short* __restrict__ kF, short* __restrict__ vF)
{
    const int tid  = threadIdx.x;
    const int lane = tid & 63;
    const int w    = tid >> 6;            // 0..7
    const int l15  = lane & 15;
    const int quad = lane >> 4;
    const int kq   = quad * 8;
    const int crow = quad * 4;
    const int job  = blockIdx.x * 8 + w;  // 0..4095 : 16-row strip
    const int laneoff = l15 * 32 + kq;

    const float* xr = x + (size_t)(job * 16 + l15) * 384 + kq;

    floatx4 acc[12] = {};

    fx4 c00 = ntload4(xr + 0);
    fx4 c01 = ntload4(xr + 4);
    fx4 c10 = ntload4(xr + 32);
    fx4 c11 = ntload4(xr + 36);

#pragma unroll
    for (int s = 0; s < 6; ++s) {
        const short8 af0 = cvt8(c00, c01);
        const short8 af1 = cvt8(c10, c11);
        // A regs free now: issue next slab's loads (used next iteration,
        // ~400+ cycles away -> HBM latency covered)
        if (s < 5) {
            c00 = ntload4(xr + (s + 1) * 64 + 0);
            c01 = ntload4(xr + (s + 1) * 64 + 4);
            c10 = ntload4(xr + (s + 1) * 64 + 32);
            c11 = ntload4(xr + (s + 1) * 64 + 36);
        }
#pragma unroll
        for (int q = 0; q < 4; ++q) {      // q = ks*2 + h
            const int ks = q >> 1, h = q & 1;
            short8 bb[6];
#pragma unroll
            for (int nt = 0; nt < 6; ++nt)
                bb[nt] = *(const short8*)
                    &WtP[((((h * 6 + s) * 2 + ks) * 6 + nt) << 9) + laneoff];
            __builtin_amdgcn_sched_barrier(0);   // keep the 6 loads batched
            const short8 af = ks ? af1 : af0;
#pragma unroll
            for (int nt = 0; nt < 6; ++nt)
                acc[h * 6 + nt] = __builtin_amdgcn_mfma_f32_16x16x32_bf16(
                    af, bb[nt], acc[h * 6 + nt], 0, 0, 0);
        }
    }

    // ---- epilogue: store q/k/v in kernel-B frag layouts -----------------
    const int b = job >> 4;     // batch
    const int g = job & 15;     // 16-row group within batch
#pragma unroll
    for (int j = 0; j < 12; ++j) {
#pragma unroll
        for (int r = 0; r < 4; ++r) {
            const float av = acc[j][r];
            if (j < 4) {
                // q: col n = j*16+l15 in [0,64): h = j>>1, kcol = (j&1)*16+l15
                qF[(((b * 16 + g) * 2 + (j >> 1)) << 9)
                   + (crow + r) * 32 + (j & 1) * 16 + l15]
                    = bf16bits(av * QSCL);
            } else if (j < 8) {
                // k: kn = n-64 in [0,64): h = (j-4)>>1, kcol = (j&1)*16+l15
                kF[(((b * 16 + g) * 2 + ((j - 4) >> 1)) << 9)
                   + (crow + r) * 32 + (j & 1) * 16 + l15]
                    = bf16bits(av);
            } else {
                // v: vcol = (j-8)*16+l15; key chunk c = g>>1,
                // keyInChunk = (g&1)*16 + crow + r
                vF[(((b * 4 + (j - 8)) * 8 + (g >> 1)) << 9)
                   + l15 * 32 + (g & 1) * 16 + crow + r]
                    = bf16bits(av);
            }
        }
    }
}

// ---------------------------------------------------------------------------
// Kernel B: causal attention. 512 blocks x 256 threads (4 waves).
// Wave wv of block half handles pair p = half*4+wv: query groups {p, 15-p}
// = exactly 9 causal 32-key chunks (perfectly balanced across all waves).
// Every q/k/v fragment is ONE 1 KB contiguous wave-load from the L2-hot
// qF/kF/vF arrays -- no staging, no __syncthreads; only LDS is the 5 KB
// wave-private Ps transpose buffer (proven m120 pattern).
// ---------------------------------------------------------------------------
__global__ __launch_bounds__(256, 4) void attn(
    const short* __restrict__ qF, const short* __restrict__ kF,
    const short* __restrict__ vF, float* __restrict__ out)
{
    __shared__ short Ps[4 * 16 * 40];   // 5120 B, wave-private slices

    const int tid  = threadIdx.x;
    const int lane = tid & 63;
    const int wv   = tid >> 6;          // 0..3
    const int l15  = lane & 15;
    const int quad = lane >> 4;
    const int kq   = quad * 8;
    const int crow = quad * 4;

    const int b = blockIdx.x >> 1;
    const int p = (blockIdx.x & 1) * 4 + wv;   // pair index 0..7

#pragma unroll
    for (int gi = 0; gi < 2; ++gi) {
        const int g  = gi ? (15 - p) : p;
        const int r0 = g * 16;

        const short8 aq0 = *(const short8*)
            &qF[(((b * 16 + g) * 2 + 0) << 9) + l15 * 32 + kq];
        const short8 aq1 = *(const short8*)
            &qF[(((b * 16 + g) * 2 + 1) << 9) + l15 * 32 + kq];

        float lsum[4] = {0.f, 0.f, 0.f, 0.f};
        floatx4 O[4] = {};

        const int nch = (r0 + 47) >> 5;   // causal chunk bound
        for (int c = 0; c < nch; ++c) {
            const int cb = c * 32;

            floatx4 st[2];
#pragma unroll
            for (int t = 0; t < 2; ++t) {
                const short8 b0 = *(const short8*)
                    &kF[(((b * 16 + (2 * c + t)) * 2 + 0) << 9) + l15 * 32 + kq];
                const short8 b1 = *(const short8*)
                    &kF[(((b * 16 + (2 * c + t)) * 2 + 1) << 9) + l15 * 32 + kq];
                floatx4 z = {};
                z = __builtin_amdgcn_mfma_f32_16x16x32_bf16(aq0, b0, z, 0, 0, 0);
                z = __builtin_amdgcn_mfma_f32_16x16x32_bf16(aq1, b1, z, 0, 0, 0);
                st[t] = z;
            }

#pragma unroll
            for (int t = 0; t < 2; ++t)
#pragma unroll
                for (int r = 0; r < 4; ++r) {
                    const int key  = cb + t * 16 + l15;
                    const int qrow = r0 + crow + r;
                    float pp = __builtin_amdgcn_exp2f(st[t][r]);
                    pp = (key <= qrow) ? pp : 0.f;
                    lsum[r] += pp;
                    Ps[wv * 640 + (crow + r) * 40 + t * 16 + l15] = bf16bits(pp);
                }

            // wave-private LDS write->read ordering
            asm volatile("s_waitcnt lgkmcnt(0)" ::: "memory");

            const short8 pa = *(const short8*)&Ps[wv * 640 + l15 * 40 + kq];
#pragma unroll
            for (int nb = 0; nb < 4; ++nb) {
                const short8 bv = *(const short8*)
                    &vF[(((b * 4 + nb) * 8 + c) << 9) + l15 * 32 + kq];
                O[nb] = __builtin_amdgcn_mfma_f32_16x16x32_bf16(pa, bv, O[nb], 0, 0, 0);
            }
        }

#pragma unroll
        for (int off = 1; off < 16; off <<= 1)
#pragma unroll
            for (int r = 0; r < 4; ++r)
                lsum[r] += __shfl_xor(lsum[r], off, 16);

        float inv[4];
#pragma unroll
        for (int r = 0; r < 4; ++r) inv[r] = 1.f / lsum[r];
#pragma unroll
        for (int nb = 0; nb < 4; ++nb)
#pragma unroll
            for (int r = 0; r < 4; ++r)
                out[(size_t)(b * 256 + r0 + crow + r) * 64 + nb * 16 + l15]
                    = O[nb][r] * inv[r];
    }
}

// ---------------------------------------------------------------------------
// Launch
// ---------------------------------------------------------------------------
extern "C" void kernel_launch(void* const* d_in, const int* in_sizes, int n_in,
                              void* d_out, int out_size, void* d_ws, size_t ws_size,
                              hipStream_t stream)
{
    const float* x  = (const float*)d_in[0];
    const float* Wq = (const float*)d_in[1];
    const float* Wk = (const float*)d_in[2];
    const float* Wv = (const float*)d_in[3];
    float* out = (float*)d_out;

    short* WtP = (short*)d_ws;             // 73728 shorts
    short* qF  = WtP + 73728;              // 4194304 shorts (8 MB)
    short* kF  = qF + 4194304;             // 4194304 shorts
    short* vF  = kF + 4194304;             // 4194304 shorts  (total ~25.3 MB)

    prep_wtp<<<(192 * 384) / 256, 256, 0, stream>>>(Wq, Wk, Wv, WtP);
    qkv_gemm<<<512, 512, 0, stream>>>(x, WtP, qF, kF, vF);
    attn<<<512, 256, 0, stream>>>(qF, kF, vF, out);
}

// Round 7
// 197.957 us; speedup vs baseline: 1.0296x; 1.0011x over previous
//
#include <hip/hip_runtime.h>
#include <hip/hip_bf16.h>
#include <math.h>

// Problem constants
#define BB   256   // batch
#define TT   256   // sequence
#define CIN  384   // n_embed
#define HS   64    // head size

// softmax scale folded into q at projection time: 384^-0.5 * log2(e)
#define QSCL ((float)(0.051031036307982884 * 1.4426950408889634))

typedef __attribute__((ext_vector_type(8))) short short8;   // 8 bf16 = 4 VGPR
typedef __attribute__((ext_vector_type(4))) float floatx4;  // MFMA C/D
typedef __attribute__((ext_vector_type(4))) float fx4;      // plain clang vec4

__device__ inline short bf16bits(float f) {
    union { __hip_bfloat16 h; short s; } u;
    u.h = __float2bfloat16(f);
    return u.s;
}

__device__ inline short8 cvt8(const fx4& f0, const fx4& f1) {
    union { __hip_bfloat162 h[4]; short8 s8; } u;
    u.h[0] = __float22bfloat162_rn(make_float2(f0.x, f0.y));
    u.h[1] = __float22bfloat162_rn(make_float2(f0.z, f0.w));
    u.h[2] = __float22bfloat162_rn(make_float2(f1.x, f1.y));
    u.h[3] = __float22bfloat162_rn(make_float2(f1.z, f1.w));
    return u.s8;
}

// nontemporal fp32x4 load (clang ext_vector type -- HIP float4 is rejected)
__device__ inline fx4 ntload4(const float* p) {
    return __builtin_nontemporal_load((const fx4*)p);
}

// ---------------------------------------------------------------------------
// Kernel 0 (unchanged): pack Wq|Wk|Wv into WtP, frag-contiguous bf16:
// X = ((h*6+s)*2+ks)*6+nt; element (l15,quad,j) at X*512 + l15*32 + quad*8 + j.
// One B-frag wave load = ONE aligned 1 KB segment.
// ---------------------------------------------------------------------------
__global__ __launch_bounds__(256) void prep_wtp(
    const float* __restrict__ Wq, const float* __restrict__ Wk,
    const float* __restrict__ Wv, short* __restrict__ WtP)
{
    const int idx  = blockIdx.x * 256 + threadIdx.x;   // 0 .. 73727
    const int j    = idx & 7;
    const int quad = (idx >> 3) & 3;
    const int l15  = (idx >> 5) & 15;
    int X          = idx >> 9;          // 0..143
    const int nt   = X % 6;  X /= 6;
    const int ks   = X & 1;  X >>= 1;
    const int s    = X % 6;  X /= 6;
    const int wn   = X;                 // 0..1

    const int n  = wn * 96 + nt * 16 + l15;        // output column 0..191
    const int kk = s * 64 + ks * 32 + quad * 8 + j; // k index 0..383
    const float* W = (n < 64) ? Wq : (n < 128) ? Wk : Wv;
    WtP[idx] = bf16bits(W[kk * 64 + (n & 63)]);
}

// ---------------------------------------------------------------------------
// Kernel A: QKV projection GEMM, M=65536 x N=192 x K=384.
// 512 blocks x 512 threads; wave = 16 rows x 192 cols (acc[12] = 48 VGPR).
// ZERO LDS, ZERO barriers.
//
// ROUND-6 FINDING: with LDS=0 the occupancy heuristic targets 8 waves/EU
// -> 64-VGPR clamp -> acc(48) leaves nothing -> B-loads serialize one at a
// time (59 us, MfmaUtil 5.7%). __launch_bounds__' 2nd arg only sets the
// MIN-waves cap; it does not stop the heuristic.
// FIX: amdgpu_waves_per_eu(4,4) pins the target at 4 waves/EU -> 128-VGPR
// budget, 16 waves/CU (= 2 co-resident 512-thread blocks, exactly this
// grid). Budget: 48 acc + 24 bb + 16 A-prefetch + 8 af + addr ~= 102 < 128.
// ---------------------------------------------------------------------------
__global__ void
__attribute__((amdgpu_flat_work_group_size(512, 512), amdgpu_waves_per_eu(4, 4)))
qkv_gemm(
    const float* __restrict__ x, const short* __restrict__ WtP,
    short* __restrict__ qF, short* __restrict__ kF, short* __restrict__ vF)
{
    const int tid  = threadIdx.x;
    const int lane = tid & 63;
    const int w    = tid >> 6;            // 0..7
    const int l15  = lane & 15;
    const int quad = lane >> 4;
    const int kq   = quad * 8;
    const int crow = quad * 4;
    const int job  = blockIdx.x * 8 + w;  // 0..4095 : 16-row strip
    const int laneoff = l15 * 32 + kq;

    const float* xr = x + (size_t)(job * 16 + l15) * 384 + kq;

    floatx4 acc[12] = {};

    fx4 c00 = ntload4(xr + 0);
    fx4 c01 = ntload4(xr + 4);
    fx4 c10 = ntload4(xr + 32);
    fx4 c11 = ntload4(xr + 36);

#pragma unroll
    for (int s = 0; s < 6; ++s) {
        const short8 af0 = cvt8(c00, c01);
        const short8 af1 = cvt8(c10, c11);
        // A regs free now: issue next slab's loads (used next iteration,
        // ~400+ cycles away -> HBM latency covered)
        if (s < 5) {
            c00 = ntload4(xr + (s + 1) * 64 + 0);
            c01 = ntload4(xr + (s + 1) * 64 + 4);
            c10 = ntload4(xr + (s + 1) * 64 + 32);
            c11 = ntload4(xr + (s + 1) * 64 + 36);
        }
#pragma unroll
        for (int q = 0; q < 4; ++q) {      // q = ks*2 + h
            const int ks = q >> 1, h = q & 1;
            short8 bb[6];
#pragma unroll
            for (int nt = 0; nt < 6; ++nt)
                bb[nt] = *(const short8*)
                    &WtP[((((h * 6 + s) * 2 + ks) * 6 + nt) << 9) + laneoff];
            __builtin_amdgcn_sched_barrier(0);   // keep the 6 loads batched
            const short8 af = ks ? af1 : af0;
#pragma unroll
            for (int nt = 0; nt < 6; ++nt)
                acc[h * 6 + nt] = __builtin_amdgcn_mfma_f32_16x16x32_bf16(
                    af, bb[nt], acc[h * 6 + nt], 0, 0, 0);
        }
    }

    // ---- epilogue: store q/k/v in kernel-B frag layouts -----------------
    const int b = job >> 4;     // batch
    const int g = job & 15;     // 16-row group within batch
#pragma unroll
    for (int j = 0; j < 12; ++j) {
#pragma unroll
        for (int r = 0; r < 4; ++r) {
            const float av = acc[j][r];
            if (j < 4) {
                // q: col n = j*16+l15 in [0,64): h = j>>1, kcol = (j&1)*16+l15
                qF[(((b * 16 + g) * 2 + (j >> 1)) << 9)
                   + (crow + r) * 32 + (j & 1) * 16 + l15]
                    = bf16bits(av * QSCL);
            } else if (j < 8) {
                // k: kn = n-64 in [0,64): h = (j-4)>>1, kcol = (j&1)*16+l15
                kF[(((b * 16 + g) * 2 + ((j - 4) >> 1)) << 9)
                   + (crow + r) * 32 + (j & 1) * 16 + l15]
                    = bf16bits(av);
            } else {
                // v: vcol = (j-8)*16+l15; key chunk c = g>>1,
                // keyInChunk = (g&1)*16 + crow + r
                vF[(((b * 4 + (j - 8)) * 8 + (g >> 1)) << 9)
                   + l15 * 32 + (g & 1) * 16 + crow + r]
                    = bf16bits(av);
            }
        }
    }
}

// ---------------------------------------------------------------------------
// Kernel B: causal attention. *** 1024 blocks x 256 threads ***; each wave
// handles ONE query group g = wv*4 + (blk&3) (the wv*4+q mapping balances
// chunk counts across blocks: 16..20 chunks/block). 2x the wave parallelism
// of round 6 and half the per-wave critical path. V-frags for the chunk are
// loaded BEFORE the softmax phase so their L2 latency hides under exp/Ps.
// Every q/k/v fragment is ONE 1 KB contiguous wave-load; only LDS is the
// 5 KB wave-private Ps transpose buffer.
// ---------------------------------------------------------------------------
__global__ void
__attribute__((amdgpu_flat_work_group_size(256, 256), amdgpu_waves_per_eu(4, 8)))
attn(
    const short* __restrict__ qF, const short* __restrict__ kF,
    const short* __restrict__ vF, float* __restrict__ out)
{
    __shared__ short Ps[4 * 16 * 40];   // 5120 B, wave-private slices

    const int tid  = threadIdx.x;
    const int lane = tid & 63;
    const int wv   = tid >> 6;          // 0..3
    const int l15  = lane & 15;
    const int quad = lane >> 4;
    const int kq   = quad * 8;
    const int crow = quad * 4;

    const int b = blockIdx.x >> 2;
    const int g = wv * 4 + (blockIdx.x & 3);   // query group 0..15
    const int r0 = g * 16;

    const short8 aq0 = *(const short8*)
        &qF[(((b * 16 + g) * 2 + 0) << 9) + l15 * 32 + kq];
    const short8 aq1 = *(const short8*)
        &qF[(((b * 16 + g) * 2 + 1) << 9) + l15 * 32 + kq];

    float lsum[4] = {0.f, 0.f, 0.f, 0.f};
    floatx4 O[4] = {};

    const int nch = (r0 + 47) >> 5;   // causal chunk bound
    for (int c = 0; c < nch; ++c) {
        const int cb = c * 32;

        // K frags for this chunk + V frags (V needed only after softmax --
        // issuing now lets L2 latency hide under QK^T + exp)
        const short8 kb00 = *(const short8*)
            &kF[(((b * 16 + (2 * c + 0)) * 2 + 0) << 9) + l15 * 32 + kq];
        const short8 kb01 = *(const short8*)
            &kF[(((b * 16 + (2 * c + 0)) * 2 + 1) << 9) + l15 * 32 + kq];
        const short8 kb10 = *(const short8*)
            &kF[(((b * 16 + (2 * c + 1)) * 2 + 0) << 9) + l15 * 32 + kq];
        const short8 kb11 = *(const short8*)
            &kF[(((b * 16 + (2 * c + 1)) * 2 + 1) << 9) + l15 * 32 + kq];
        short8 bv[4];
#pragma unroll
        for (int nb = 0; nb < 4; ++nb)
            bv[nb] = *(const short8*)
                &vF[(((b * 4 + nb) * 8 + c) << 9) + l15 * 32 + kq];
        __builtin_amdgcn_sched_barrier(0);

        floatx4 st[2];
        {
            floatx4 z = {};
            z = __builtin_amdgcn_mfma_f32_16x16x32_bf16(aq0, kb00, z, 0, 0, 0);
            z = __builtin_amdgcn_mfma_f32_16x16x32_bf16(aq1, kb01, z, 0, 0, 0);
            st[0] = z;
        }
        {
            floatx4 z = {};
            z = __builtin_amdgcn_mfma_f32_16x16x32_bf16(aq0, kb10, z, 0, 0, 0);
            z = __builtin_amdgcn_mfma_f32_16x16x32_bf16(aq1, kb11, z, 0, 0, 0);
            st[1] = z;
        }

#pragma unroll
        for (int t = 0; t < 2; ++t)
#pragma unroll
            for (int r = 0; r < 4; ++r) {
                const int key  = cb + t * 16 + l15;
                const int qrow = r0 + crow + r;
                float pp = __builtin_amdgcn_exp2f(st[t][r]);
                pp = (key <= qrow) ? pp : 0.f;
                lsum[r] += pp;
                Ps[wv * 640 + (crow + r) * 40 + t * 16 + l15] = bf16bits(pp);
            }

        // wave-private LDS write->read ordering
        asm volatile("s_waitcnt lgkmcnt(0)" ::: "memory");

        const short8 pa = *(const short8*)&Ps[wv * 640 + l15 * 40 + kq];
#pragma unroll
        for (int nb = 0; nb < 4; ++nb)
            O[nb] = __builtin_amdgcn_mfma_f32_16x16x32_bf16(pa, bv[nb], O[nb], 0, 0, 0);
    }

#pragma unroll
    for (int off = 1; off < 16; off <<= 1)
#pragma unroll
        for (int r = 0; r < 4; ++r)
            lsum[r] += __shfl_xor(lsum[r], off, 16);

    float inv[4];
#pragma unroll
    for (int r = 0; r < 4; ++r) inv[r] = 1.f / lsum[r];
#pragma unroll
    for (int nb = 0; nb < 4; ++nb)
#pragma unroll
        for (int r = 0; r < 4; ++r)
            out[(size_t)(b * 256 + r0 + crow + r) * 64 + nb * 16 + l15]
                = O[nb][r] * inv[r];
}

// ---------------------------------------------------------------------------
// Launch
// ---------------------------------------------------------------------------
extern "C" void kernel_launch(void* const* d_in, const int* in_sizes, int n_in,
                              void* d_out, int out_size, void* d_ws, size_t ws_size,
                              hipStream_t stream)
{
    const float* x  = (const float*)d_in[0];
    const float* Wq = (const float*)d_in[1];
    const float* Wk = (const float*)d_in[2];
    const float* Wv = (const float*)d_in[3];
    float* out = (float*)d_out;

    short* WtP = (short*)d_ws;             // 73728 shorts
    short* qF  = WtP + 73728;              // 4194304 shorts (8 MB)
    short* kF  = qF + 4194304;             // 4194304 shorts
    short* vF  = kF + 4194304;             // 4194304 shorts  (total ~25.3 MB)

    prep_wtp<<<(192 * 384) / 256, 256, 0, stream>>>(Wq, Wk, Wv, WtP);
    qkv_gemm<<<512, 512, 0, stream>>>(x, WtP, qF, kF, vF);
    attn<<<1024, 256, 0, stream>>>(qF, kF, vF, out);
}